// Round 7
// baseline (31.397 us; speedup 1.0000x reference)
//
#include <hip/hip_runtime.h>

// Problem constants (fixed by the reference)
#define NTOT 512   // N
#define NH   448   // N - K (identity head)
#define KK   64    // K (solved tail rows)
#define NL   30688 // strictly-lower entries in last K rows
#define DD   16    // domains
#define BB   1024  // batch
#define SLICES 32  // apply blocks per domain
#define MAXG 2     // samples per group iteration
#define LISTCAP 1024

// ws layout (bytes):
//   [0,64)            counts[16] (int)
//   [1024, 1024+64K)  lists[16][1024] (int)
//   [66560, +2MB)     Wq: [dom][(c>>2)*256 + r*4 + (c&3)] f32
#define WS_LISTS_OFF 1024
#define WS_W_OFF     66560

// W_d = (I-U_d)^{-1} [T_d | diag(s_d)] (64x512); z_tail = W_d @ eps.
// L_emb[dom] row m: T[m][0:448] at m*448+m(m-1)/2, then U[m][0:m].
// buildW is COLUMN-parallel: lane = column, substitution runs over rows r with
// U[r][m] wave-uniform (LDS broadcast) and rhs T[r][c] lane-contiguous
// (coalesced) -- no uncoalesced gathers, no shfl chains (r5/r6's limiter).
// XCD locality: buildW block bid = tile*16+dom and apply bid = slice*16+dom
// both land on XCD dom%8 (round-robin heuristic) so W_d stays in that L2.

// ---------- Kernel A: 128 buildW blocks (1 wave each) + 16 scan blocks ----------
__global__ __launch_bounds__(64)
void fvae_prep(const int*   __restrict__ dom_idx,  // [B]
               const float* __restrict__ L_emb,    // [16, NL]
               const float* __restrict__ S_emb,    // [16, 64]
               float*       __restrict__ ws)
{
    const int bid  = blockIdx.x;
    const int lane = threadIdx.x;   // 0..63

    __shared__ float U_s[(KK * (KK - 1)) / 2];   // packed strictly-lower, 8KB

    if (bid >= 128) {
        // ---- ballot-rank scan for domain bid-128 (all chunk loads prefetched)
        const int dom = bid - 128;
        int* counts = (int*)ws;
        int* lists  = (int*)((char*)ws + WS_LISTS_OFF) + dom * LISTCAP;
        int dm[BB / 64];
        #pragma unroll
        for (int t = 0; t < BB / 64; ++t) dm[t] = dom_idx[t * 64 + lane];
        int base = 0;
        #pragma unroll
        for (int t = 0; t < BB / 64; ++t) {
            const unsigned long long mt = __ballot(dm[t] == dom);
            if (dm[t] == dom) {
                const int rank = base + __popcll(mt & ((1ull << lane) - 1ull));
                lists[rank] = t * 64 + lane;
            }
            base += __popcll(mt);
        }
        if (lane == 0) counts[dom] = base;
        return;
    }

    // ---- buildW: bid = tile*16 + dom; this wave owns columns c = tile*64+lane
    const int dom  = bid & 15;
    const int tile = bid >> 4;         // 0..7
    const int c    = tile * 64 + lane; // 0..511
    float* __restrict__ Wd = (float*)((char*)ws + WS_W_OFF) + (size_t)dom * (NTOT * KK);

    if (dom == 0) {                    // L=0, S=I -> W = [0 | I]
        #pragma unroll
        for (int r = 0; r < KK; ++r)
            Wd[(c >> 2) * 256 + r * 4 + (c & 3)] = (c - NH == r) ? 1.f : 0.f;
        return;
    }

    const float* __restrict__ Ld = L_emb + (size_t)dom * NL;

    // stage packed U coalesced: row r contiguous (r floats at r*448+r(r-1)/2+448)
    for (int r = 1; r < KK; ++r)
        if (lane < r)
            U_s[(r * (r - 1)) / 2 + lane] = Ld[r * NH + (r * (r - 1)) / 2 + NH + lane];

    // rhs prefetch into w[] (coalesced: lane = column), fully static-indexed
    float w[KK];
    if (tile < 7) {
        #pragma unroll
        for (int r = 0; r < KK; ++r)
            w[r] = Ld[r * NH + (r * (r - 1)) / 2 + c];   // T[r][c]
    } else {
        const float sm = S_emb[dom * KK + lane];
        #pragma unroll
        for (int r = 0; r < KK; ++r)
            w[r] = (lane == r) ? sm : 0.f;               // diag(s) block
    }
    __syncthreads();

    // column-parallel forward substitution: w[r] += sum_{m<r} U[r][m] * w[m]
    // U_s reads are wave-uniform -> LDS broadcast (no conflicts, no shuffles)
    #pragma unroll
    for (int r = 1; r < KK; ++r) {
        const int rb = (r * (r - 1)) / 2;
        float a0 = 0.f, a1 = 0.f;
        #pragma unroll
        for (int m = 0; m + 1 < r; m += 2) {
            a0 += U_s[rb + m]     * w[m];
            a1 += U_s[rb + m + 1] * w[m + 1];
        }
        if (r & 1) a0 += U_s[rb + r - 1] * w[r - 1];     // compile-time per r
        w[r] += a0 + a1;
    }

    #pragma unroll
    for (int r = 0; r < KK; ++r)
        Wd[(c >> 2) * 256 + r * 4 + (c & 3)] = w[r];
}

// ---------- Kernel B: grouped matvec, 2 samples share every W load ----------
__global__ __launch_bounds__(256)
void fvae_apply(const float* __restrict__ eps,      // [B,512]
                const float* __restrict__ bias_ns,  // [16, 64]
                const float* __restrict__ bias_sh,  // [448]
                const float* __restrict__ ws,
                float*       __restrict__ out)      // [B,512]
{
    const int dom   = blockIdx.x & 15;   // XCD dom%8, matches buildW writers
    const int slice = blockIdx.x >> 4;   // 0..31
    const int tid   = threadIdx.x;
    const int w     = tid >> 6;
    const int l     = tid & 63;

    __shared__ float eps_s[MAXG][NTOT];
    __shared__ float part_s[4][MAXG][KK];
    __shared__ int   idx_s[MAXG];

    const int*   counts = (const int*)ws;
    const int*   lists  = (const int*)((const char*)ws + WS_LISTS_OFF) + dom * LISTCAP;
    const float* __restrict__ Wd =
        (const float*)((const char*)ws + WS_W_OFF) + (size_t)dom * (NTOT * KK);

    const int cnt     = counts[dom];
    const int G_total = (cnt > slice) ? (cnt - 1 - slice) / SLICES + 1 : 0;
    if (G_total == 0) return;

    for (int s0 = 0; s0 < G_total; s0 += MAXG) {
        const int Gc = min(MAXG, G_total - s0);
        if (tid < Gc) idx_s[tid] = lists[slice + (s0 + tid) * SLICES];
        __syncthreads();

        // stage eps rows (float4, coalesced)
        for (int v = tid; v < Gc * (NTOT / 4); v += 256) {
            const int g = v >> 7, q = v & 127;
            *(float4*)&eps_s[g][q * 4] =
                *(const float4*)(eps + (size_t)idx_s[g] * NTOT + q * 4);
        }
        __syncthreads();

        // head: out[:,0:448] = eps + bias_sh
        for (int v = tid; v < Gc * (NH / 4); v += 256) {
            const int g = v / 112, q = v - g * 112;
            const float4 e  = *(const float4*)&eps_s[g][q * 4];
            const float4 bs = *(const float4*)(bias_sh + q * 4);
            float4 o; o.x = e.x + bs.x; o.y = e.y + bs.y;
            o.z = e.z + bs.z; o.w = e.w + bs.w;
            *(float4*)(out + (size_t)idx_s[g] * NTOT + q * 4) = o;
        }

        // matvec: lane = output row; wave w covers q = i*4+w (32 indep float4)
        float acc[MAXG];
        #pragma unroll
        for (int g = 0; g < MAXG; ++g) acc[g] = 0.f;
        #pragma unroll
        for (int i = 0; i < 32; ++i) {
            const int q = i * 4 + w;
            const float4 Wv = *(const float4*)(Wd + q * 256 + l * 4);  // 1KB/wave
            #pragma unroll
            for (int g = 0; g < MAXG; ++g) {
                const float4 e = *(const float4*)&eps_s[g][q * 4];     // broadcast
                acc[g] += Wv.x * e.x + Wv.y * e.y + Wv.z * e.z + Wv.w * e.w;
            }
        }
        #pragma unroll
        for (int g = 0; g < MAXG; ++g) part_s[w][g][l] = acc[g];
        __syncthreads();

        // cross-wave reduce + tail write
        if (tid < MAXG * KK) {
            const int g = tid >> 6, r = tid & 63;
            if (g < Gc) {
                const float z = part_s[0][g][r] + part_s[1][g][r]
                              + part_s[2][g][r] + part_s[3][g][r];
                out[(size_t)idx_s[g] * NTOT + NH + r] = z + bias_ns[dom * KK + r];
            }
        }
        __syncthreads();
    }
}

extern "C" void kernel_launch(void* const* d_in, const int* in_sizes, int n_in,
                              void* d_out, int out_size, void* d_ws, size_t ws_size,
                              hipStream_t stream) {
    const float* eps     = (const float*)d_in[0];
    const int*   dom     = (const int*)  d_in[1];
    const float* L_emb   = (const float*)d_in[2];
    const float* S_emb   = (const float*)d_in[3];
    const float* bias_ns = (const float*)d_in[4];
    const float* bias_sh = (const float*)d_in[5];
    float* out = (float*)d_out;
    float* ws  = (float*)d_ws;

    fvae_prep <<<dim3(128 + DD),    dim3(64),  0, stream>>>(dom, L_emb, S_emb, ws);
    fvae_apply<<<dim3(DD * SLICES), dim3(256), 0, stream>>>(eps, bias_ns, bias_sh,
                                                            ws, out);
}